// Round 1
// baseline (821.860 us; speedup 1.0000x reference)
//
#include <hip/hip_runtime.h>
#include <hip/hip_bf16.h>
#include <cmath>

#define B_ 4096
#define D_ 768
#define E_ 16
#define H_ 768
#define C_ 1000
#define CP_ 1024
#define K_ 768

typedef __bf16 bf16_t;
typedef __bf16 bf16x8 __attribute__((ext_vector_type(8)));
typedef float f32x4 __attribute__((ext_vector_type(4)));

__device__ __forceinline__ void async_lds16(const void* g, void* l) {
  __builtin_amdgcn_global_load_lds(
      (const __attribute__((address_space(1))) void*)g,
      (__attribute__((address_space(3))) void*)l, 16, 0, 0);
}

// ---------------- router: gate logits (fp32) + softmax + top-4 ----------------
__global__ __launch_bounds__(256) void k_router(
    const float* __restrict__ feat, const float* __restrict__ rw,
    const float* __restrict__ rb, float* __restrict__ gate_out,
    int* __restrict__ tk_idx, float* __restrict__ tk_val) {
  int w = threadIdx.x >> 6, lane = threadIdx.x & 63;
  int b = blockIdx.x * 4 + w;
  float acc[E_];
#pragma unroll
  for (int e = 0; e < E_; ++e) acc[e] = 0.f;
  const float* frow = feat + (size_t)b * D_;
#pragma unroll
  for (int it = 0; it < D_ / 64; ++it) {
    int d = it * 64 + lane;
    float f = frow[d];
    const float4* r4 = reinterpret_cast<const float4*>(rw + (size_t)d * E_);
    float4 q0 = r4[0], q1 = r4[1], q2 = r4[2], q3 = r4[3];
    acc[0]  += f * q0.x; acc[1]  += f * q0.y; acc[2]  += f * q0.z; acc[3]  += f * q0.w;
    acc[4]  += f * q1.x; acc[5]  += f * q1.y; acc[6]  += f * q1.z; acc[7]  += f * q1.w;
    acc[8]  += f * q2.x; acc[9]  += f * q2.y; acc[10] += f * q2.z; acc[11] += f * q2.w;
    acc[12] += f * q3.x; acc[13] += f * q3.y; acc[14] += f * q3.z; acc[15] += f * q3.w;
  }
#pragma unroll
  for (int e = 0; e < E_; ++e) {
#pragma unroll
    for (int off = 32; off; off >>= 1) acc[e] += __shfl_xor(acc[e], off);
    acc[e] += rb[e];
  }
  if (lane == 0) {
    float mx = acc[0];
#pragma unroll
    for (int e = 1; e < E_; ++e) mx = fmaxf(mx, acc[e]);
    float p[E_];
    float s = 0.f;
#pragma unroll
    for (int e = 0; e < E_; ++e) { p[e] = expf(acc[e] - mx); s += p[e]; }
    float inv = 1.f / s;
    float* go = gate_out + (size_t)b * E_;
#pragma unroll
    for (int e = 0; e < E_; ++e) { p[e] *= inv; go[e] = p[e]; }
    // top-4 on logits (same order as probs); strict > keeps lowest index on ties
    float lg[E_];
#pragma unroll
    for (int e = 0; e < E_; ++e) lg[e] = acc[e];
    int idx4[4]; float v4[4]; float vs = 0.f;
#pragma unroll
    for (int k = 0; k < 4; ++k) {
      int bi = 0; float bv = -1e30f;
#pragma unroll
      for (int e = 0; e < E_; ++e) { if (lg[e] > bv) { bv = lg[e]; bi = e; } }
      idx4[k] = bi; v4[k] = p[bi]; vs += p[bi]; lg[bi] = -1e30f;
    }
    float nv = 1.f / vs;
#pragma unroll
    for (int k = 0; k < 4; ++k) { tk_idx[b * 4 + k] = idx4[k]; tk_val[b * 4 + k] = v4[k] * nv; }
  }
}

// ---------------- LayerNorm stats -> xn (bf16) ----------------
__global__ __launch_bounds__(256) void k_ln(const float* __restrict__ feat,
                                            bf16_t* __restrict__ xn) {
  int w = threadIdx.x >> 6, lane = threadIdx.x & 63;
  int b = blockIdx.x * 4 + w;
  const float* x = feat + (size_t)b * D_;
  float v[D_ / 64];
  float s = 0.f, sq = 0.f;
#pragma unroll
  for (int i = 0; i < D_ / 64; ++i) {
    v[i] = x[i * 64 + lane];
    s += v[i]; sq += v[i] * v[i];
  }
#pragma unroll
  for (int off = 32; off; off >>= 1) { s += __shfl_xor(s, off); sq += __shfl_xor(sq, off); }
  float mu = s * (1.f / D_);
  float var = sq * (1.f / D_) - mu * mu;
  float rs = rsqrtf(var + 1e-5f);
  bf16_t* o = xn + (size_t)b * D_;
#pragma unroll
  for (int i = 0; i < D_ / 64; ++i)
    o[i * 64 + lane] = (bf16_t)((v[i] - mu) * rs);
}

// ---------------- transpose+convert w1 (fold ln_g): w1T[e][h][d] = bf16(g[e][d]*w1[e][d][h]) ----
__global__ void k_tw1(const float* __restrict__ w1, const float* __restrict__ lng,
                      bf16_t* __restrict__ w1T) {
  __shared__ float t[32][33];
  int e = blockIdx.z, dT = blockIdx.y * 32, hT = blockIdx.x * 32;
  int tx = threadIdx.x, ty = threadIdx.y;
  const float* w1e = w1 + (size_t)e * D_ * H_;
  const float* ge = lng + (size_t)e * D_;
#pragma unroll
  for (int r = 0; r < 4; ++r) {
    int d = dT + ty + r * 8;
    t[ty + r * 8][tx] = w1e[(size_t)d * H_ + hT + tx] * ge[d];
  }
  __syncthreads();
  bf16_t* o = w1T + (size_t)e * H_ * D_;
#pragma unroll
  for (int r = 0; r < 4; ++r) {
    int h = hT + ty + r * 8;
    o[(size_t)h * D_ + dT + tx] = (bf16_t)t[tx][ty + r * 8];
  }
}

// ---------------- transpose+convert w2 (pad C->1024 with zeros): w2T[e][c][h] ----------------
__global__ void k_tw2(const float* __restrict__ w2, bf16_t* __restrict__ w2T) {
  __shared__ float t[32][33];
  int e = blockIdx.z, hT = blockIdx.y * 32, cT = blockIdx.x * 32;
  int tx = threadIdx.x, ty = threadIdx.y;
  const float* w2e = w2 + (size_t)e * H_ * C_;
#pragma unroll
  for (int r = 0; r < 4; ++r) {
    int h = hT + ty + r * 8, c = cT + tx;
    t[ty + r * 8][tx] = (c < C_) ? w2e[(size_t)h * C_ + c] : 0.f;
  }
  __syncthreads();
  bf16_t* o = w2T + (size_t)e * CP_ * H_;
#pragma unroll
  for (int r = 0; r < 4; ++r) {
    int c = cT + ty + r * 8;
    o[(size_t)c * H_ + hT + tx] = (bf16_t)t[tx][ty + r * 8];
  }
}

// ---------------- effective bias1 = b1 + ln_b @ w1 (split-K partials) ----------------
__global__ __launch_bounds__(256) void k_bias_part(const float* __restrict__ w1,
                                                   const float* __restrict__ lnb,
                                                   float* __restrict__ pb) {
  int e = blockIdx.z, z = blockIdx.y;
  int h = blockIdx.x * 256 + threadIdx.x;
  const float* w1e = w1 + (size_t)e * D_ * H_;
  const float* lb = lnb + (size_t)e * D_;
  float acc = 0.f;
  int d0 = z * (D_ / 8);
#pragma unroll 8
  for (int d = d0; d < d0 + D_ / 8; ++d) acc += lb[d] * w1e[(size_t)d * H_ + h];
  pb[((size_t)e * 8 + z) * H_ + h] = acc;
}

__global__ __launch_bounds__(256) void k_bias_comb(const float* __restrict__ b1,
                                                   const float* __restrict__ pb,
                                                   float* __restrict__ bias1) {
  int e = blockIdx.y;
  int h = blockIdx.x * 256 + threadIdx.x;
  float a = b1[(size_t)e * H_ + h];
#pragma unroll
  for (int z = 0; z < 8; ++z) a += pb[((size_t)e * 8 + z) * H_ + h];
  bias1[(size_t)e * H_ + h] = a;
}

// ---------------- m97-style bf16 MFMA GEMM: C[M,N] = A[M,K] * Bt[N,K]^T + bias ----------------
// MODE 0: out = bf16(GELU_exact(C)) -> Hact[e][m][n]   (N=768)
// MODE 1: out = fp32 C -> logits[e][m][n], n<1000      (N padded 1024)
template <int MODE>
__global__ __launch_bounds__(256) void k_gemm(
    const bf16_t* __restrict__ Abase, size_t aStride,
    const bf16_t* __restrict__ Bt, int Np,
    const float* __restrict__ bias,
    bf16_t* __restrict__ outb, float* __restrict__ outf) {
  __shared__ __attribute__((aligned(16))) bf16_t As[128 * 32];
  __shared__ __attribute__((aligned(16))) bf16_t Bs[128 * 32];
  int e = blockIdx.z;
  int m0 = blockIdx.y * 128, n0 = blockIdx.x * 128;
  const bf16_t* A = Abase + (size_t)e * aStride;
  const bf16_t* Be = Bt + ((size_t)e * Np + n0) * K_;
  int tid = threadIdx.x;
  int lane = tid & 63, w = tid >> 6;
  int wm = (w & 1) * 64, wn = (w >> 1) * 64;
  int fr = lane & 15, fk = (lane >> 4) * 8;

  f32x4 acc[4][4];
#pragma unroll
  for (int i = 0; i < 4; ++i)
#pragma unroll
    for (int j = 0; j < 4; ++j) acc[i][j] = f32x4{0.f, 0.f, 0.f, 0.f};

  int r0 = tid >> 2;             // tile row for staging (0..63)
  int c0 = (tid & 3) * 8;        // k offset within BK=32
  const bf16_t* a_src0 = A + (size_t)(m0 + r0) * K_ + c0;
  const bf16_t* a_src1 = A + (size_t)(m0 + r0 + 64) * K_ + c0;
  const bf16_t* b_src0 = Be + (size_t)r0 * K_ + c0;
  const bf16_t* b_src1 = Be + (size_t)(r0 + 64) * K_ + c0;
  bf16_t* a_dst0 = As + tid * 8;
  bf16_t* a_dst1 = As + 2048 + tid * 8;
  bf16_t* b_dst0 = Bs + tid * 8;
  bf16_t* b_dst1 = Bs + 2048 + tid * 8;

  for (int kk = 0; kk < K_; kk += 32) {
    async_lds16(a_src0 + kk, a_dst0);
    async_lds16(a_src1 + kk, a_dst1);
    async_lds16(b_src0 + kk, b_dst0);
    async_lds16(b_src1 + kk, b_dst1);
    __syncthreads();
    bf16x8 afr[4], bfr[4];
#pragma unroll
    for (int i = 0; i < 4; ++i)
      afr[i] = *(const bf16x8*)&As[(wm + i * 16 + fr) * 32 + fk];
#pragma unroll
    for (int i = 0; i < 4; ++i)
      bfr[i] = *(const bf16x8*)&Bs[(wn + i * 16 + fr) * 32 + fk];
#pragma unroll
    for (int i = 0; i < 4; ++i)
#pragma unroll
      for (int j = 0; j < 4; ++j)
        acc[i][j] = __builtin_amdgcn_mfma_f32_16x16x32_bf16(afr[i], bfr[j], acc[i][j], 0, 0, 0);
    __syncthreads();
  }

  // epilogue — C/D layout: col = lane&15, row = (lane>>4)*4 + reg
  int rbse = (lane >> 4) * 4;
  int cl = lane & 15;
#pragma unroll
  for (int i = 0; i < 4; ++i) {
#pragma unroll
    for (int j = 0; j < 4; ++j) {
      int n = n0 + wn + j * 16 + cl;
      if (MODE == 0) {
        float bs = bias[(size_t)e * H_ + n];
#pragma unroll
        for (int r = 0; r < 4; ++r) {
          int m = m0 + wm + i * 16 + rbse + r;
          float v = acc[i][j][r] + bs;
          v = 0.5f * v * (1.f + erff(v * 0.70710678118654752f));
          outb[((size_t)e * B_ + m) * H_ + n] = (bf16_t)v;
        }
      } else {
        if (n < C_) {
          float bs = bias[(size_t)e * C_ + n];
#pragma unroll
          for (int r = 0; r < 4; ++r) {
            int m = m0 + wm + i * 16 + rbse + r;
            outf[((size_t)e * B_ + m) * C_ + n] = acc[i][j][r] + bs;
          }
        }
      }
    }
  }
}

// ---------------- in-place row softmax over C=1000 ----------------
__global__ __launch_bounds__(256) void k_softmax(float* __restrict__ p) {
  int w = threadIdx.x >> 6, lane = threadIdx.x & 63;
  size_t r = (size_t)blockIdx.x * 4 + w;
  float* row = p + r * C_;
  float4* row4 = reinterpret_cast<float4*>(row);
  const int n4 = C_ / 4;  // 250
  float4 v[4];
  float mx = -1e30f;
#pragma unroll
  for (int i = 0; i < 4; ++i) {
    int idx = i * 64 + lane;
    if (idx < n4) {
      v[i] = row4[idx];
      mx = fmaxf(mx, fmaxf(fmaxf(v[i].x, v[i].y), fmaxf(v[i].z, v[i].w)));
    }
  }
#pragma unroll
  for (int off = 32; off; off >>= 1) mx = fmaxf(mx, __shfl_xor(mx, off));
  float s = 0.f;
#pragma unroll
  for (int i = 0; i < 4; ++i) {
    int idx = i * 64 + lane;
    if (idx < n4) {
      v[i].x = __expf(v[i].x - mx); v[i].y = __expf(v[i].y - mx);
      v[i].z = __expf(v[i].z - mx); v[i].w = __expf(v[i].w - mx);
      s += v[i].x + v[i].y + v[i].z + v[i].w;
    }
  }
#pragma unroll
  for (int off = 32; off; off >>= 1) s += __shfl_xor(s, off);
  float inv = 1.f / s;
#pragma unroll
  for (int i = 0; i < 4; ++i) {
    int idx = i * 64 + lane;
    if (idx < n4) {
      v[i].x *= inv; v[i].y *= inv; v[i].z *= inv; v[i].w *= inv;
      row4[idx] = v[i];
    }
  }
}

// ---------------- market_probs = sum_k tkv[b,k] * all_probs[tki[b,k]][b][:] ----------------
__global__ __launch_bounds__(256) void k_market(const float* __restrict__ allp,
                                                const int* __restrict__ tki,
                                                const float* __restrict__ tkv,
                                                float* __restrict__ out0) {
  int b = blockIdx.y;
  int c = blockIdx.x * 256 + threadIdx.x;
  if (c >= C_) return;
  const int* ix = tki + (size_t)b * 4;
  const float* vv = tkv + (size_t)b * 4;
  float s = 0.f;
#pragma unroll
  for (int k = 0; k < 4; ++k)
    s += vv[k] * allp[((size_t)ix[k] * B_ + b) * C_ + c];
  out0[(size_t)b * C_ + c] = s;
}

extern "C" void kernel_launch(void* const* d_in, const int* in_sizes, int n_in,
                              void* d_out, int out_size, void* d_ws, size_t ws_size,
                              hipStream_t stream) {
  const float* feat = (const float*)d_in[0];
  const float* rw   = (const float*)d_in[1];
  const float* rb   = (const float*)d_in[2];
  const float* lng  = (const float*)d_in[3];
  const float* lnb  = (const float*)d_in[4];
  const float* w1   = (const float*)d_in[5];
  const float* b1   = (const float*)d_in[6];
  const float* w2   = (const float*)d_in[7];
  const float* b2   = (const float*)d_in[8];

  float* out0 = (float*)d_out;                   // market_probs [4096,1000]
  float* out1 = out0 + (size_t)B_ * C_;          // all_probs [16,4096,1000]
  float* out2 = out1 + (size_t)E_ * B_ * C_;     // gate_probs [4096,16]

  char* ws = (char*)d_ws;
  size_t off = 0;
  auto take = [&](size_t bytes) -> void* {
    void* p = ws + off;
    off += (bytes + 255) & ~(size_t)255;
    return p;
  };
  bf16_t* xn   = (bf16_t*)take((size_t)B_ * D_ * 2);
  bf16_t* w1T  = (bf16_t*)take((size_t)E_ * H_ * D_ * 2);
  bf16_t* w2T  = (bf16_t*)take((size_t)E_ * CP_ * H_ * 2);
  float* bias1 = (float*)take((size_t)E_ * H_ * 4);
  float* pb    = (float*)take((size_t)E_ * 8 * H_ * 4);
  int* tki     = (int*)take((size_t)B_ * 4 * 4);
  float* tkv   = (float*)take((size_t)B_ * 4 * 4);
  bf16_t* Hact = (bf16_t*)take((size_t)E_ * B_ * H_ * 2);

  k_router<<<B_ / 4, 256, 0, stream>>>(feat, rw, rb, out2, tki, tkv);
  k_ln<<<B_ / 4, 256, 0, stream>>>(feat, xn);
  k_tw1<<<dim3(24, 24, E_), dim3(32, 8), 0, stream>>>(w1, lng, w1T);
  k_tw2<<<dim3(32, 24, E_), dim3(32, 8), 0, stream>>>(w2, w2T);
  k_bias_part<<<dim3(3, 8, E_), 256, 0, stream>>>(w1, lnb, pb);
  k_bias_comb<<<dim3(3, E_), 256, 0, stream>>>(b1, pb, bias1);
  k_gemm<0><<<dim3(6, 32, E_), 256, 0, stream>>>(xn, 0, w1T, H_, bias1, Hact, nullptr);
  k_gemm<1><<<dim3(8, 32, E_), 256, 0, stream>>>(Hact, (size_t)B_ * H_, w2T, CP_, b2, nullptr, out1);
  k_softmax<<<(E_ * B_) / 4, 256, 0, stream>>>(out1);
  k_market<<<dim3(4, B_), 256, 0, stream>>>(out1, tki, tkv, out0);
}

// Round 2
// 705.662 us; speedup vs baseline: 1.1647x; 1.1647x over previous
//
#include <hip/hip_runtime.h>
#include <hip/hip_bf16.h>
#include <cmath>

#define B_ 4096
#define D_ 768
#define E_ 16
#define H_ 768
#define C_ 1000
#define CP_ 1024
#define K_ 768

typedef __bf16 bf16_t;
typedef __bf16 bf16x8 __attribute__((ext_vector_type(8)));
typedef float f32x4 __attribute__((ext_vector_type(4)));

__device__ __forceinline__ void async_lds16(const void* g, void* l) {
  __builtin_amdgcn_global_load_lds(
      (const __attribute__((address_space(1))) void*)g,
      (__attribute__((address_space(3))) void*)l, 16, 0, 0);
}

// ---------------- router + LayerNorm fused (both read feat once) ----------------
__global__ __launch_bounds__(256) void k_router_ln(
    const float* __restrict__ feat, const float* __restrict__ rw,
    const float* __restrict__ rb, float* __restrict__ gate_out,
    int* __restrict__ tk_idx, float* __restrict__ tk_val,
    bf16_t* __restrict__ xn) {
  int w = threadIdx.x >> 6, lane = threadIdx.x & 63;
  int b = blockIdx.x * 4 + w;
  float acc[E_];
#pragma unroll
  for (int e = 0; e < E_; ++e) acc[e] = 0.f;
  const float* frow = feat + (size_t)b * D_;
  float v[D_ / 64];
  float s = 0.f, sq = 0.f;
#pragma unroll
  for (int it = 0; it < D_ / 64; ++it) {
    int d = it * 64 + lane;
    float f = frow[d];
    v[it] = f; s += f; sq += f * f;
    const float4* r4 = reinterpret_cast<const float4*>(rw + (size_t)d * E_);
    float4 q0 = r4[0], q1 = r4[1], q2 = r4[2], q3 = r4[3];
    acc[0]  += f * q0.x; acc[1]  += f * q0.y; acc[2]  += f * q0.z; acc[3]  += f * q0.w;
    acc[4]  += f * q1.x; acc[5]  += f * q1.y; acc[6]  += f * q1.z; acc[7]  += f * q1.w;
    acc[8]  += f * q2.x; acc[9]  += f * q2.y; acc[10] += f * q2.z; acc[11] += f * q2.w;
    acc[12] += f * q3.x; acc[13] += f * q3.y; acc[14] += f * q3.z; acc[15] += f * q3.w;
  }
#pragma unroll
  for (int off = 32; off; off >>= 1) { s += __shfl_xor(s, off); sq += __shfl_xor(sq, off); }
  float mu = s * (1.f / D_);
  float var = sq * (1.f / D_) - mu * mu;
  float rs = rsqrtf(var + 1e-5f);
  bf16_t* o = xn + (size_t)b * D_;
#pragma unroll
  for (int it = 0; it < D_ / 64; ++it)
    o[it * 64 + lane] = (bf16_t)((v[it] - mu) * rs);
#pragma unroll
  for (int e = 0; e < E_; ++e) {
#pragma unroll
    for (int off = 32; off; off >>= 1) acc[e] += __shfl_xor(acc[e], off);
    acc[e] += rb[e];
  }
  if (lane == 0) {
    float mx = acc[0];
#pragma unroll
    for (int e = 1; e < E_; ++e) mx = fmaxf(mx, acc[e]);
    float p[E_]; float ps = 0.f;
#pragma unroll
    for (int e = 0; e < E_; ++e) { p[e] = expf(acc[e] - mx); ps += p[e]; }
    float inv = 1.f / ps;
    float* go = gate_out + (size_t)b * E_;
#pragma unroll
    for (int e = 0; e < E_; ++e) { p[e] *= inv; go[e] = p[e]; }
    float lg[E_];
#pragma unroll
    for (int e = 0; e < E_; ++e) lg[e] = acc[e];
    int idx4[4]; float v4[4]; float vs = 0.f;
#pragma unroll
    for (int k = 0; k < 4; ++k) {
      int bi = 0; float bv = -1e30f;
#pragma unroll
      for (int e = 0; e < E_; ++e) { if (lg[e] > bv) { bv = lg[e]; bi = e; } }
      idx4[k] = bi; v4[k] = p[bi]; vs += p[bi]; lg[bi] = -1e30f;
    }
    float nv = 1.f / vs;
#pragma unroll
    for (int k = 0; k < 4; ++k) { tk_idx[b * 4 + k] = idx4[k]; tk_val[b * 4 + k] = v4[k] * nv; }
  }
}

// ---------------- bias1 init: bias1 = b1 ----------------
__global__ __launch_bounds__(256) void k_bias_init(const float* __restrict__ b1,
                                                   float* __restrict__ bias1) {
  int i = blockIdx.x * 256 + threadIdx.x;
  bias1[i] = b1[i];
}

// ---- transpose+convert w1 (fold ln_g) + accumulate bias contrib lnb@w1 ----
__global__ void k_tw1(const float* __restrict__ w1, const float* __restrict__ lng,
                      const float* __restrict__ lnb, bf16_t* __restrict__ w1T,
                      float* __restrict__ bias1) {
  __shared__ float t[32][33];
  __shared__ float br[8][33];
  int e = blockIdx.z, dT = blockIdx.y * 32, hT = blockIdx.x * 32;
  int tx = threadIdx.x, ty = threadIdx.y;
  const float* w1e = w1 + (size_t)e * D_ * H_;
  const float* ge = lng + (size_t)e * D_;
  const float* lb = lnb + (size_t)e * D_;
  float bsum = 0.f;
#pragma unroll
  for (int r = 0; r < 4; ++r) {
    int d = dT + ty + r * 8;
    float val = w1e[(size_t)d * H_ + hT + tx];
    t[ty + r * 8][tx] = val * ge[d];
    bsum += lb[d] * val;
  }
  br[ty][tx] = bsum;
  __syncthreads();
  bf16_t* o = w1T + (size_t)e * H_ * D_;
#pragma unroll
  for (int r = 0; r < 4; ++r) {
    int h = hT + ty + r * 8;
    o[(size_t)h * D_ + dT + tx] = (bf16_t)t[tx][ty + r * 8];
  }
  if (ty == 0) {
    float a = 0.f;
#pragma unroll
    for (int z = 0; z < 8; ++z) a += br[z][tx];
    atomicAdd(&bias1[(size_t)e * H_ + hT + tx], a);
  }
}

// ---------------- transpose+convert w2 (pad C->1024 with zeros): w2T[e][c][h] ----------------
__global__ void k_tw2(const float* __restrict__ w2, bf16_t* __restrict__ w2T) {
  __shared__ float t[32][33];
  int e = blockIdx.z, hT = blockIdx.y * 32, cT = blockIdx.x * 32;
  int tx = threadIdx.x, ty = threadIdx.y;
  const float* w2e = w2 + (size_t)e * H_ * C_;
#pragma unroll
  for (int r = 0; r < 4; ++r) {
    int h = hT + ty + r * 8, c = cT + tx;
    t[ty + r * 8][tx] = (c < C_) ? w2e[(size_t)h * C_ + c] : 0.f;
  }
  __syncthreads();
  bf16_t* o = w2T + (size_t)e * CP_ * H_;
#pragma unroll
  for (int r = 0; r < 4; ++r) {
    int c = cT + ty + r * 8;
    o[(size_t)c * H_ + hT + tx] = (bf16_t)t[tx][ty + r * 8];
  }
}

// ---------------- m97-style bf16 MFMA GEMM, XCD-swizzled 1D grid ----------------
// Tiles: 128x128, BK=32. Per-XCD: E_/8=2 whole experts, n fastest (A-tile L2 reuse).
// MODE 0: out = bf16(GELU_exact(C+bias1)) -> Hact[e][m][n], stride H_     (NT=6)
// MODE 1: out = bf16(C+b2) -> logits[e][m][n], stride CP_ (all 1024 cols) (NT=8)
// MODE 2: out = fp32(C+b2) -> out1[e][m][n], stride C_, n<1000           (NT=8)
template <int MODE, int NT>
__global__ __launch_bounds__(256) void k_gemm(
    const bf16_t* __restrict__ Abase, size_t aStride,
    const bf16_t* __restrict__ Bt, int Np,
    const float* __restrict__ bias,
    bf16_t* __restrict__ outb, float* __restrict__ outf) {
  __shared__ __attribute__((aligned(16))) bf16_t As[128 * 32];
  __shared__ __attribute__((aligned(16))) bf16_t Bs[128 * 32];
  int id = blockIdx.x;
  int xcd = id & 7, seq = id >> 3;
  const int PER_E = 32 * NT;
  int e = xcd * (E_ / 8) + seq / PER_E;
  int rem = seq % PER_E;
  int m0 = (rem / NT) * 128, n0 = (rem % NT) * 128;

  const bf16_t* A = Abase + (size_t)e * aStride;
  const bf16_t* Be = Bt + ((size_t)e * Np + n0) * K_;
  int tid = threadIdx.x;
  int lane = tid & 63, w = tid >> 6;
  int wm = (w & 1) * 64, wn = (w >> 1) * 64;
  int fr = lane & 15, fk = (lane >> 4) * 8;

  f32x4 acc[4][4];
#pragma unroll
  for (int i = 0; i < 4; ++i)
#pragma unroll
    for (int j = 0; j < 4; ++j) acc[i][j] = f32x4{0.f, 0.f, 0.f, 0.f};

  int r0 = tid >> 2;
  int c0 = (tid & 3) * 8;
  const bf16_t* a_src0 = A + (size_t)(m0 + r0) * K_ + c0;
  const bf16_t* a_src1 = A + (size_t)(m0 + r0 + 64) * K_ + c0;
  const bf16_t* b_src0 = Be + (size_t)r0 * K_ + c0;
  const bf16_t* b_src1 = Be + (size_t)(r0 + 64) * K_ + c0;
  bf16_t* a_dst0 = As + tid * 8;
  bf16_t* a_dst1 = As + 2048 + tid * 8;
  bf16_t* b_dst0 = Bs + tid * 8;
  bf16_t* b_dst1 = Bs + 2048 + tid * 8;

  for (int kk = 0; kk < K_; kk += 32) {
    async_lds16(a_src0 + kk, a_dst0);
    async_lds16(a_src1 + kk, a_dst1);
    async_lds16(b_src0 + kk, b_dst0);
    async_lds16(b_src1 + kk, b_dst1);
    __syncthreads();
    bf16x8 afr[4], bfr[4];
#pragma unroll
    for (int i = 0; i < 4; ++i)
      afr[i] = *(const bf16x8*)&As[(wm + i * 16 + fr) * 32 + fk];
#pragma unroll
    for (int i = 0; i < 4; ++i)
      bfr[i] = *(const bf16x8*)&Bs[(wn + i * 16 + fr) * 32 + fk];
#pragma unroll
    for (int i = 0; i < 4; ++i)
#pragma unroll
      for (int j = 0; j < 4; ++j)
        acc[i][j] = __builtin_amdgcn_mfma_f32_16x16x32_bf16(afr[i], bfr[j], acc[i][j], 0, 0, 0);
    __syncthreads();
  }

  // epilogue — C/D layout: col = lane&15, row = (lane>>4)*4 + reg
  int rbse = (lane >> 4) * 4;
  int cl = lane & 15;
#pragma unroll
  for (int i = 0; i < 4; ++i) {
#pragma unroll
    for (int j = 0; j < 4; ++j) {
      int n = n0 + wn + j * 16 + cl;
      if (MODE == 0) {
        float bs = bias[(size_t)e * H_ + n];
#pragma unroll
        for (int r = 0; r < 4; ++r) {
          int m = m0 + wm + i * 16 + rbse + r;
          float vv = acc[i][j][r] + bs;
          vv = 0.5f * vv * (1.f + erff(vv * 0.70710678118654752f));
          outb[((size_t)e * B_ + m) * H_ + n] = (bf16_t)vv;
        }
      } else if (MODE == 1) {
        float bs = (n < C_) ? bias[(size_t)e * C_ + n] : 0.f;
#pragma unroll
        for (int r = 0; r < 4; ++r) {
          int m = m0 + wm + i * 16 + rbse + r;
          outb[((size_t)e * B_ + m) * CP_ + n] = (bf16_t)(acc[i][j][r] + bs);
        }
      } else {
        if (n < C_) {
          float bs = bias[(size_t)e * C_ + n];
#pragma unroll
          for (int r = 0; r < 4; ++r) {
            int m = m0 + wm + i * 16 + rbse + r;
            outf[((size_t)e * B_ + m) * C_ + n] = acc[i][j][r] + bs;
          }
        }
      }
    }
  }
}

// ---------------- softmax from bf16 logits (stride CP_) -> fp32 probs (stride C_) ----------------
__global__ __launch_bounds__(256) void k_softmax_b(const bf16_t* __restrict__ lg,
                                                   float* __restrict__ out1) {
  int w = threadIdx.x >> 6, lane = threadIdx.x & 63;
  size_t r = (size_t)blockIdx.x * 4 + w;
  const bf16_t* row = lg + r * CP_;
  float f[2][8];
  float mx = -1e30f;
#pragma unroll
  for (int it = 0; it < 2; ++it) {
    int ch = it * 64 + lane;           // 8-elem chunk index; valid if < 125
    bf16x8 x = *(const bf16x8*)(row + ch * 8);
    if (ch < 125) {
#pragma unroll
      for (int q = 0; q < 8; ++q) { f[it][q] = (float)x[q]; mx = fmaxf(mx, f[it][q]); }
    }
  }
#pragma unroll
  for (int off = 32; off; off >>= 1) mx = fmaxf(mx, __shfl_xor(mx, off));
  float s = 0.f;
#pragma unroll
  for (int it = 0; it < 2; ++it) {
    int ch = it * 64 + lane;
    if (ch < 125) {
#pragma unroll
      for (int q = 0; q < 8; ++q) { f[it][q] = __expf(f[it][q] - mx); s += f[it][q]; }
    }
  }
#pragma unroll
  for (int off = 32; off; off >>= 1) s += __shfl_xor(s, off);
  float inv = 1.f / s;
  float* orow = out1 + r * C_;
#pragma unroll
  for (int it = 0; it < 2; ++it) {
    int ch = it * 64 + lane;
    if (ch < 125) {
      float4 a = make_float4(f[it][0] * inv, f[it][1] * inv, f[it][2] * inv, f[it][3] * inv);
      float4 b = make_float4(f[it][4] * inv, f[it][5] * inv, f[it][6] * inv, f[it][7] * inv);
      *(float4*)(orow + ch * 8) = a;
      *(float4*)(orow + ch * 8 + 4) = b;
    }
  }
}

// ---------------- in-place fp32 row softmax over C=1000 (fallback path) ----------------
__global__ __launch_bounds__(256) void k_softmax(float* __restrict__ p) {
  int w = threadIdx.x >> 6, lane = threadIdx.x & 63;
  size_t r = (size_t)blockIdx.x * 4 + w;
  float* row = p + r * C_;
  float4* row4 = reinterpret_cast<float4*>(row);
  const int n4 = C_ / 4;
  float4 v[4];
  float mx = -1e30f;
#pragma unroll
  for (int i = 0; i < 4; ++i) {
    int idx = i * 64 + lane;
    if (idx < n4) {
      v[i] = row4[idx];
      mx = fmaxf(mx, fmaxf(fmaxf(v[i].x, v[i].y), fmaxf(v[i].z, v[i].w)));
    }
  }
#pragma unroll
  for (int off = 32; off; off >>= 1) mx = fmaxf(mx, __shfl_xor(mx, off));
  float s = 0.f;
#pragma unroll
  for (int i = 0; i < 4; ++i) {
    int idx = i * 64 + lane;
    if (idx < n4) {
      v[i].x = __expf(v[i].x - mx); v[i].y = __expf(v[i].y - mx);
      v[i].z = __expf(v[i].z - mx); v[i].w = __expf(v[i].w - mx);
      s += v[i].x + v[i].y + v[i].z + v[i].w;
    }
  }
#pragma unroll
  for (int off = 32; off; off >>= 1) s += __shfl_xor(s, off);
  float inv = 1.f / s;
#pragma unroll
  for (int i = 0; i < 4; ++i) {
    int idx = i * 64 + lane;
    if (idx < n4) {
      v[i].x *= inv; v[i].y *= inv; v[i].z *= inv; v[i].w *= inv;
      row4[idx] = v[i];
    }
  }
}

// ---------------- market_probs = sum_k tkv[b,k] * all_probs[tki[b,k]][b][:] ----------------
__global__ __launch_bounds__(256) void k_market(const float* __restrict__ allp,
                                                const int* __restrict__ tki,
                                                const float* __restrict__ tkv,
                                                float* __restrict__ out0) {
  int b = blockIdx.y;
  int c = blockIdx.x * 256 + threadIdx.x;
  if (c >= C_) return;
  const int* ix = tki + (size_t)b * 4;
  const float* vv = tkv + (size_t)b * 4;
  float s = 0.f;
#pragma unroll
  for (int k = 0; k < 4; ++k)
    s += vv[k] * allp[((size_t)ix[k] * B_ + b) * C_ + c];
  out0[(size_t)b * C_ + c] = s;
}

extern "C" void kernel_launch(void* const* d_in, const int* in_sizes, int n_in,
                              void* d_out, int out_size, void* d_ws, size_t ws_size,
                              hipStream_t stream) {
  const float* feat = (const float*)d_in[0];
  const float* rw   = (const float*)d_in[1];
  const float* rb   = (const float*)d_in[2];
  const float* lng  = (const float*)d_in[3];
  const float* lnb  = (const float*)d_in[4];
  const float* w1   = (const float*)d_in[5];
  const float* b1   = (const float*)d_in[6];
  const float* w2   = (const float*)d_in[7];
  const float* b2   = (const float*)d_in[8];

  float* out0 = (float*)d_out;                   // market_probs [4096,1000]
  float* out1 = out0 + (size_t)B_ * C_;          // all_probs [16,4096,1000]
  float* out2 = out1 + (size_t)E_ * B_ * C_;     // gate_probs [4096,16]

  char* ws = (char*)d_ws;
  size_t off = 0;
  auto take = [&](size_t bytes) -> void* {
    void* p = ws + off;
    off += (bytes + 255) & ~(size_t)255;
    return p;
  };
  bf16_t* xn   = (bf16_t*)take((size_t)B_ * D_ * 2);
  bf16_t* w1T  = (bf16_t*)take((size_t)E_ * H_ * D_ * 2);
  bf16_t* w2T  = (bf16_t*)take((size_t)E_ * CP_ * H_ * 2);
  float* bias1 = (float*)take((size_t)E_ * H_ * 4);
  int* tki     = (int*)take((size_t)B_ * 4 * 4);
  float* tkv   = (float*)take((size_t)B_ * 4 * 4);
  bf16_t* Hact = (bf16_t*)take((size_t)E_ * B_ * H_ * 2);
  size_t logit_bytes = (size_t)E_ * B_ * CP_ * 2;
  bool use_b16_logits = (off + logit_bytes) <= ws_size;   // constant across calls: graph-safe
  bf16_t* logitsB = use_b16_logits ? (bf16_t*)take(logit_bytes) : nullptr;

  k_router_ln<<<B_ / 4, 256, 0, stream>>>(feat, rw, rb, out2, tki, tkv, xn);
  k_bias_init<<<E_ * H_ / 256, 256, 0, stream>>>(b1, bias1);
  k_tw1<<<dim3(24, 24, E_), dim3(32, 8), 0, stream>>>(w1, lng, lnb, w1T, bias1);
  k_tw2<<<dim3(32, 24, E_), dim3(32, 8), 0, stream>>>(w2, w2T);
  k_gemm<0, 6><<<E_ * 32 * 6, 256, 0, stream>>>(xn, 0, w1T, H_, bias1, Hact, nullptr);
  if (use_b16_logits) {
    k_gemm<1, 8><<<E_ * 32 * 8, 256, 0, stream>>>(Hact, (size_t)B_ * H_, w2T, CP_, b2, logitsB, nullptr);
    k_softmax_b<<<(E_ * B_) / 4, 256, 0, stream>>>(logitsB, out1);
  } else {
    k_gemm<2, 8><<<E_ * 32 * 8, 256, 0, stream>>>(Hact, (size_t)B_ * H_, w2T, CP_, b2, nullptr, out1);
    k_softmax<<<(E_ * B_) / 4, 256, 0, stream>>>(out1);
  }
  k_market<<<dim3(4, B_), 256, 0, stream>>>(out1, tki, tkv, out0);
}